// Round 12
// baseline (229.213 us; speedup 1.0000x reference)
//
#include <hip/hip_runtime.h>
#include <stdint.h>

#define M_DIM 8192
#define N_DIM 4096
#define K_DIM 4096

typedef float f32x4  __attribute__((ext_vector_type(4)));
typedef float f32x16 __attribute__((ext_vector_type(16)));
typedef int   i32x4  __attribute__((ext_vector_type(4)));
typedef int   i32x8  __attribute__((ext_vector_type(8)));

// ---------------- fused amax (x and w) via uint-bits atomicMax ----------------
__global__ __launch_bounds__(256) void amax2_kernel(const float* __restrict__ x,
                                                    const float* __restrict__ wgt,
                                                    unsigned int* __restrict__ ws_u) {
    const int which = blockIdx.y;
    const float4* p = (const float4*)(which ? wgt : x);
    const int n4 = (which ? N_DIM : M_DIM) * (K_DIM / 4);
    int tid = blockIdx.x * blockDim.x + threadIdx.x;
    int stride = gridDim.x * blockDim.x;
    float m = 0.0f;
    for (int i = tid; i < n4; i += stride) {
        float4 v = p[i];
        m = fmaxf(m, fmaxf(fmaxf(fabsf(v.x), fabsf(v.y)),
                           fmaxf(fabsf(v.z), fabsf(v.w))));
    }
#pragma unroll
    for (int off = 32; off > 0; off >>= 1)
        m = fmaxf(m, __shfl_down(m, off, 64));
    __shared__ float sm[4];
    if ((threadIdx.x & 63) == 0) sm[threadIdx.x >> 6] = m;
    __syncthreads();
    if (threadIdx.x == 0) {
        m = fmaxf(fmaxf(sm[0], sm[1]), fmaxf(sm[2], sm[3]));
        atomicMax(ws_u + which, __float_as_uint(m));  // values >= 0: bit order == float order
    }
}

// ---------------- fused quantize f32 -> fp8 e4m3fn (packed 4/uint) -------------
__global__ __launch_bounds__(256) void quant2_kernel(const float* __restrict__ x,
                                                     const float* __restrict__ wgt,
                                                     unsigned int* __restrict__ xq,
                                                     unsigned int* __restrict__ wq,
                                                     const unsigned int* __restrict__ ws_u) {
    const int which = blockIdx.y;
    const float4* p = (const float4*)(which ? wgt : x);
    unsigned int* outp = which ? wq : xq;
    const int n4 = (which ? N_DIM : M_DIM) * (K_DIM / 4);
    float amax = fmaxf(__uint_as_float(ws_u[which]), 1e-12f);
    float scale = 448.0f / amax;
    int tid = blockIdx.x * blockDim.x + threadIdx.x;
    int stride = gridDim.x * blockDim.x;
    for (int i = tid; i < n4; i += stride) {
        float4 v = p[i];
        float a = fminf(fmaxf(v.x * scale, -448.0f), 448.0f);
        float b = fminf(fmaxf(v.y * scale, -448.0f), 448.0f);
        float c = fminf(fmaxf(v.z * scale, -448.0f), 448.0f);
        float d = fminf(fmaxf(v.w * scale, -448.0f), 448.0f);
        int w = __builtin_amdgcn_cvt_pk_fp8_f32(a, b, 0, false);
        w = __builtin_amdgcn_cvt_pk_fp8_f32(c, d, w, true);
        outp[i] = (unsigned int)w;
    }
}

// ------- MX-fp8 GEMM: 256x256, 4 waves, 128x128/wave, SW-pipelined sub-phases --
__device__ __forceinline__ void gld16(const void* g, void* l) {
    __builtin_amdgcn_global_load_lds(
        (const __attribute__((address_space(1))) void*)g,
        (__attribute__((address_space(3))) void*)l, 16, 0, 0);
}

#define MFMA32(a, b, c) __builtin_amdgcn_mfma_scale_f32_32x32x64_f8f6f4( \
    (a), (b), (c), 0, 0, 0, 0x7F7F7F7F, 0, 0x7F7F7F7F)
#define BAR()    __builtin_amdgcn_s_barrier()
#define VMCNT(n) asm volatile("s_waitcnt vmcnt(" #n ")" ::: "memory")
#define LGKM0()  asm volatile("s_waitcnt lgkmcnt(0)" ::: "memory")
#define PRIO1()  __builtin_amdgcn_s_setprio(1)
#define PRIO0()  __builtin_amdgcn_s_setprio(0)

// R11 structure with the boundary race FIXED. Per tile t:
//   top: stage(t+1) -> buf^1 (16 gld16)
//   S0 {read b01,a1 || 8 MFMA a0xb00}  S1 {read b10 || 8 MFMA a0xb01}
//   S2 {read b11 || 8 MFMA a1xb10}
//   boundary (t<31): lgkmcnt(0)  [b11 issued ~550cyc ago -> free; retires ALL
//                     ds_reads of both buffers]
//                    vmcnt(0)    [stages issued ~1650cyc ago > HBM latency]
//                    BAR         [=> no wave has any outstanding LDS read or
//                                 stage write: next-tile staging race-free]
//                    pre-read alpha(t+1) from nbuf  [lands under S3]
//   S3 {8 MFMA a1xb11}
// Each sub-phase's operands in DISJOINT registers (a0/a1/b00/b01/b10/b11) so
// in-order issue streams ds_reads into the ~8-cyc gaps between blocking
// 69-cyc MFMAs -- DS pipe (1536cyc/tile) hides under matrix pipe (2200cyc).
// Swizzle: 16B-chunk XOR (chunk ^= row&7), linear dest, pre-swizzled global
// source, XOR on read (rule #21; verified R3-R10, absmax stable 0.015625).
__global__ __launch_bounds__(256, 1) void gemm_fp8_kernel(
    const uint8_t* __restrict__ Aq,   // [M][K] fp8
    const uint8_t* __restrict__ Bq,   // [N][K] fp8
    const float* __restrict__ bias,   // [N]
    const unsigned int* __restrict__ ws_u,
    float* __restrict__ out)          // [M][N] f32
{
    __shared__ uint8_t lds[131072];   // A bufs [0,64K), B bufs [64K,128K)

    const int tid = threadIdx.x;
    const int w = tid >> 6, l = tid & 63;

    // XCD swizzle (512 blocks, %8==0): 32 M-tiles x 16 N-tiles
    const int cpx = (int)gridDim.x >> 3;
    const int bid = (int)blockIdx.x;
    const int swz = (bid & 7) * cpx + (bid >> 3);
    const int bm = swz >> 4, bn = swz & 15;

    const uint8_t* gA = Aq + (size_t)bm * 256 * K_DIM;
    const uint8_t* gB = Bq + (size_t)bn * 256 * K_DIM;

    // staging: thread t -> row half*128 + r*32 + idx; dest chunk p; src p^(idx&7)
    const int idx = tid >> 3, p = tid & 7;
    const int srcX = ((p ^ (idx & 7)) << 4);
    const uint8_t* aRow = gA + (size_t)idx * K_DIM + srcX;
    const uint8_t* bRow = gB + (size_t)idx * K_DIM + srcX;
    const int dA = tid * 16;

    // fragment constants: 2x2 wave grid, 128x128 per wave, 32x32x64 frags
    const int wr = w >> 1, wc = w & 1;
    const int lr = l & 31;
    const int hi2 = (l >> 5) << 1;
    const int rowA0 = wr * 128 + lr;
    const int rowB0 = wc * 128 + lr;

    auto stageA = [&](int bb, int kn, int half) {
#pragma unroll
        for (int r = 0; r < 4; ++r)
            gld16(aRow + (size_t)(half * 128 + r * 32) * K_DIM + kn,
                  &lds[bb * 32768 + half * 16384 + r * 4096 + dA]);
    };
    auto stageB = [&](int bb, int kn, int half) {
#pragma unroll
        for (int r = 0; r < 4; ++r)
            gld16(bRow + (size_t)(half * 128 + r * 32) * K_DIM + kn,
                  &lds[65536 + bb * 32768 + half * 16384 + r * 4096 + dA]);
    };
    auto ldf = [&](const uint8_t* base, int row, int kh) -> i32x8 {
        const uint8_t* q = base + (row << 7);
        const int rk = row & 7;
        const int c0 = (kh << 2) + hi2;
        i32x4 lo = *(const i32x4*)(q + ((c0 ^ rk) << 4));
        i32x4 hh = *(const i32x4*)(q + (((c0 + 1) ^ rk) << 4));
        return __builtin_shufflevector(lo, hh, 0, 1, 2, 3, 4, 5, 6, 7);
    };

    f32x16 acc[4][4] = {};
    i32x8 a0[4], a1[4], b00[2], b01[2], b10[2], b11[2];

    // prologue: stage tile 0 -> buf 0; read S0's operands (alpha set)
    stageA(0, 0, 0); stageB(0, 0, 0);
    stageA(0, 0, 1); stageB(0, 0, 1);
    VMCNT(0); BAR();
    a0[0] = ldf(&lds[0], rowA0, 0);       a0[1] = ldf(&lds[0], rowA0 + 32, 0);
    a0[2] = ldf(&lds[0], rowA0 + 64, 0);  a0[3] = ldf(&lds[0], rowA0 + 96, 0);
    b00[0] = ldf(&lds[65536], rowB0, 0);  b00[1] = ldf(&lds[65536], rowB0 + 32, 0);

    for (int t = 0; t < 32; ++t) {
        const int buf = t & 1;
        const uint8_t* lab = &lds[buf * 32768];
        const uint8_t* lbb = &lds[65536 + buf * 32768];
        const int kn = (t + 1) * 128;

        // prefetch tile t+1 into the opposite buffer (race-free: at the last
        // barrier every wave had lgkmcnt==0, so no reads of that buffer remain)
        if (t < 31) {
            stageA(buf ^ 1, kn, 0); stageB(buf ^ 1, kn, 0);
            stageA(buf ^ 1, kn, 1); stageB(buf ^ 1, kn, 1);
        }

        // ---- S0: issue beta reads (b01, a1); MFMA a0 x b00
        b01[0] = ldf(lbb, rowB0 + 64, 0); b01[1] = ldf(lbb, rowB0 + 96, 0);
        a1[0] = ldf(lab, rowA0, 1);       a1[1] = ldf(lab, rowA0 + 32, 1);
        a1[2] = ldf(lab, rowA0 + 64, 1);  a1[3] = ldf(lab, rowA0 + 96, 1);
        PRIO1();
        acc[0][0] = MFMA32(a0[0], b00[0], acc[0][0]);
        acc[0][1] = MFMA32(a0[0], b00[1], acc[0][1]);
        acc[1][0] = MFMA32(a0[1], b00[0], acc[1][0]);
        acc[1][1] = MFMA32(a0[1], b00[1], acc[1][1]);
        acc[2][0] = MFMA32(a0[2], b00[0], acc[2][0]);
        acc[2][1] = MFMA32(a0[2], b00[1], acc[2][1]);
        acc[3][0] = MFMA32(a0[3], b00[0], acc[3][0]);
        acc[3][1] = MFMA32(a0[3], b00[1], acc[3][1]);
        PRIO0();

        // ---- S1: issue gamma reads (b10); MFMA a0 x b01
        b10[0] = ldf(lbb, rowB0, 1);      b10[1] = ldf(lbb, rowB0 + 32, 1);
        PRIO1();
        acc[0][2] = MFMA32(a0[0], b01[0], acc[0][2]);
        acc[0][3] = MFMA32(a0[0], b01[1], acc[0][3]);
        acc[1][2] = MFMA32(a0[1], b01[0], acc[1][2]);
        acc[1][3] = MFMA32(a0[1], b01[1], acc[1][3]);
        acc[2][2] = MFMA32(a0[2], b01[0], acc[2][2]);
        acc[2][3] = MFMA32(a0[2], b01[1], acc[2][3]);
        acc[3][2] = MFMA32(a0[3], b01[0], acc[3][2]);
        acc[3][3] = MFMA32(a0[3], b01[1], acc[3][3]);
        PRIO0();

        // ---- S2: issue delta reads (b11); MFMA a1 x b10
        b11[0] = ldf(lbb, rowB0 + 64, 1); b11[1] = ldf(lbb, rowB0 + 96, 1);
        PRIO1();
        acc[0][0] = MFMA32(a1[0], b10[0], acc[0][0]);
        acc[0][1] = MFMA32(a1[0], b10[1], acc[0][1]);
        acc[1][0] = MFMA32(a1[1], b10[0], acc[1][0]);
        acc[1][1] = MFMA32(a1[1], b10[1], acc[1][1]);
        acc[2][0] = MFMA32(a1[2], b10[0], acc[2][0]);
        acc[2][1] = MFMA32(a1[2], b10[1], acc[2][1]);
        acc[3][0] = MFMA32(a1[3], b10[0], acc[3][0]);
        acc[3][1] = MFMA32(a1[3], b10[1], acc[3][1]);
        PRIO0();

        // ---- boundary BEFORE S3: drain reads (free) + stages (free), sync,
        //      pre-read tile t+1's alpha set so it lands under S3's MFMAs.
        if (t < 31) {
            LGKM0();                 // b11 issued ~550 cyc ago -> no stall;
                                     // retires ALL of this wave's ds_reads
            VMCNT(0);                // stages issued ~1650 cyc ago -> no stall
            BAR();                   // all waves: zero LDS reads/writes pending
            const uint8_t* nlab = &lds[(buf ^ 1) * 32768];
            const uint8_t* nlbb = &lds[65536 + (buf ^ 1) * 32768];
            a0[0] = ldf(nlab, rowA0, 0);      a0[1] = ldf(nlab, rowA0 + 32, 0);
            a0[2] = ldf(nlab, rowA0 + 64, 0); a0[3] = ldf(nlab, rowA0 + 96, 0);
            b00[0] = ldf(nlbb, rowB0, 0);     b00[1] = ldf(nlbb, rowB0 + 32, 0);
        }

        // ---- S3: MFMA a1 x b11 (alpha pre-reads complete underneath)
        PRIO1();
        acc[0][2] = MFMA32(a1[0], b11[0], acc[0][2]);
        acc[0][3] = MFMA32(a1[0], b11[1], acc[0][3]);
        acc[1][2] = MFMA32(a1[1], b11[0], acc[1][2]);
        acc[1][3] = MFMA32(a1[1], b11[1], acc[1][3]);
        acc[2][2] = MFMA32(a1[2], b11[0], acc[2][2]);
        acc[2][3] = MFMA32(a1[2], b11[1], acc[2][3]);
        acc[3][2] = MFMA32(a1[3], b11[0], acc[3][2]);
        acc[3][3] = MFMA32(a1[3], b11[1], acc[3][3]);
        PRIO0();
    }

    // ---- epilogue: scale by (amax_x/448)*(amax_w/448), add bias
    const float ax = fmaxf(__uint_as_float(ws_u[0]), 1e-12f);
    const float aw = fmaxf(__uint_as_float(ws_u[1]), 1e-12f);
    const float inv = (ax * (1.0f / 448.0f)) * (aw * (1.0f / 448.0f));

    // 32x32 D: col = lane&31, row = (reg&3) + 8*(reg>>2) + 4*(lane>>5)
    const int orow0 = bm * 256 + wr * 128 + ((l >> 5) << 2);
    const int ocol0 = bn * 256 + wc * 128 + lr;
#pragma unroll
    for (int mb = 0; mb < 4; ++mb) {
#pragma unroll
        for (int nb = 0; nb < 4; ++nb) {
            const int col = ocol0 + nb * 32;
            const float bvv = bias[col];
#pragma unroll
            for (int r = 0; r < 16; ++r) {
                const int row = orow0 + mb * 32 + (r & 3) + ((r >> 2) << 3);
                out[(size_t)row * N_DIM + col] = acc[mb][nb][r] * inv + bvv;
            }
        }
    }
}

// ---------------- launch ----------------
extern "C" void kernel_launch(void* const* d_in, const int* in_sizes, int n_in,
                              void* d_out, int out_size, void* d_ws, size_t ws_size,
                              hipStream_t stream) {
    const float* x    = (const float*)d_in[0];   // [8192, 4096]
    const float* wgt  = (const float*)d_in[1];   // [4096, 4096]
    const float* bias = (const float*)d_in[2];   // [4096]
    float* out = (float*)d_out;                  // [8192, 4096] f32

    unsigned int* ws_u = (unsigned int*)d_ws;
    uint8_t* xq = (uint8_t*)d_ws + 256;
    uint8_t* wq = xq + (size_t)M_DIM * K_DIM;

    hipMemsetAsync(d_ws, 0, 8, stream);          // zero both amax slots

    dim3 ga(1024, 2);
    amax2_kernel<<<ga, 256, 0, stream>>>(x, wgt, ws_u);

    dim3 gq(2048, 2);
    quant2_kernel<<<gq, 256, 0, stream>>>(x, wgt, (unsigned int*)xq,
                                          (unsigned int*)wq, ws_u);

    gemm_fp8_kernel<<<(M_DIM / 256) * (N_DIM / 256), 256, 0, stream>>>(
        xq, wq, bias, ws_u, out);
}

// Round 13
// 211.939 us; speedup vs baseline: 1.0815x; 1.0815x over previous
//
#include <hip/hip_runtime.h>
#include <stdint.h>

#define M_DIM 8192
#define N_DIM 4096
#define K_DIM 4096

typedef float f32x4 __attribute__((ext_vector_type(4)));
typedef int   i32x4 __attribute__((ext_vector_type(4)));
typedef int   i32x8 __attribute__((ext_vector_type(8)));

// ---------------- fused amax (x and w) via uint-bits atomicMax ----------------
__global__ __launch_bounds__(256) void amax2_kernel(const float* __restrict__ x,
                                                    const float* __restrict__ wgt,
                                                    unsigned int* __restrict__ ws_u) {
    const int which = blockIdx.y;
    const float4* p = (const float4*)(which ? wgt : x);
    const int n4 = (which ? N_DIM : M_DIM) * (K_DIM / 4);
    int tid = blockIdx.x * blockDim.x + threadIdx.x;
    int stride = gridDim.x * blockDim.x;
    float m = 0.0f;
    for (int i = tid; i < n4; i += stride) {
        float4 v = p[i];
        m = fmaxf(m, fmaxf(fmaxf(fabsf(v.x), fabsf(v.y)),
                           fmaxf(fabsf(v.z), fabsf(v.w))));
    }
#pragma unroll
    for (int off = 32; off > 0; off >>= 1)
        m = fmaxf(m, __shfl_down(m, off, 64));
    __shared__ float sm[4];
    if ((threadIdx.x & 63) == 0) sm[threadIdx.x >> 6] = m;
    __syncthreads();
    if (threadIdx.x == 0) {
        m = fmaxf(fmaxf(sm[0], sm[1]), fmaxf(sm[2], sm[3]));
        atomicMax(ws_u + which, __float_as_uint(m));  // values >= 0: bit order == float order
    }
}

// ---------------- fused quantize f32 -> fp8 e4m3fn (packed 4/uint) -------------
__global__ __launch_bounds__(256) void quant2_kernel(const float* __restrict__ x,
                                                     const float* __restrict__ wgt,
                                                     unsigned int* __restrict__ xq,
                                                     unsigned int* __restrict__ wq,
                                                     const unsigned int* __restrict__ ws_u) {
    const int which = blockIdx.y;
    const float4* p = (const float4*)(which ? wgt : x);
    unsigned int* outp = which ? wq : xq;
    const int n4 = (which ? N_DIM : M_DIM) * (K_DIM / 4);
    float amax = fmaxf(__uint_as_float(ws_u[which]), 1e-12f);
    float scale = 448.0f / amax;
    int tid = blockIdx.x * blockDim.x + threadIdx.x;
    int stride = gridDim.x * blockDim.x;
    for (int i = tid; i < n4; i += stride) {
        float4 v = p[i];
        float a = fminf(fmaxf(v.x * scale, -448.0f), 448.0f);
        float b = fminf(fmaxf(v.y * scale, -448.0f), 448.0f);
        float c = fminf(fmaxf(v.z * scale, -448.0f), 448.0f);
        float d = fminf(fmaxf(v.w * scale, -448.0f), 448.0f);
        int w = __builtin_amdgcn_cvt_pk_fp8_f32(a, b, 0, false);
        w = __builtin_amdgcn_cvt_pk_fp8_f32(c, d, w, true);
        outp[i] = (unsigned int)w;
    }
}

// ---------------- MX-fp8 GEMM, 256x256 tile, 4-phase pipelined ----------------
// (R4's measured-best kernel, verbatim: 130 us, MfmaUtil 45%)
__device__ __forceinline__ void gld16(const void* g, void* l) {
    __builtin_amdgcn_global_load_lds(
        (const __attribute__((address_space(1))) void*)g,
        (__attribute__((address_space(3))) void*)l, 16, 0, 0);
}

#define MFMA_MX(a, b, c) __builtin_amdgcn_mfma_scale_f32_16x16x128_f8f6f4( \
    (a), (b), (c), 0, 0, 0, 0x7F7F7F7F, 0, 0x7F7F7F7F)

// LDS: A bufs at [0,32K),[32K,64K); B bufs at [64K,96K),[96K,128K).
// Per-tensor tile [256 rows][128 B], 16B-chunk XOR swizzle (chunk ^= row&7),
// staged linearly (pre-swizzled global source), read with XOR on address.
// Pipeline: tile t read from buf t&1; tile t+1's 4 units staged one-per-phase
// into buf^1. Counted vmcnt only: ledger (2 loads/unit, issue order
// UA0,UB0,UA1,UB1 per tile) => phase0 needs UA0,UB0 -> vmcnt(4);
// phase1 needs UA1,UB1 -> vmcnt(2). Never 0 in the main loop.
__global__ __launch_bounds__(512, 2) void gemm_fp8_kernel(
    const uint8_t* __restrict__ Aq,   // [M][K] fp8
    const uint8_t* __restrict__ Bq,   // [N][K] fp8
    const float* __restrict__ bias,   // [N]
    const unsigned int* __restrict__ ws_u,
    float* __restrict__ out)          // [M][N] f32
{
    __shared__ uint8_t lds[131072];

    const int tid = threadIdx.x;
    const int w = tid >> 6, l = tid & 63;

    // XCD swizzle (512 blocks, %8==0): 32 M-tiles x 16 N-tiles
    const int cpx = (int)gridDim.x >> 3;
    const int bid = (int)blockIdx.x;
    const int swz = (bid & 7) * cpx + (bid >> 3);
    const int bm = swz >> 4, bn = swz & 15;

    const uint8_t* gA = Aq + (size_t)bm * 256 * K_DIM;
    const uint8_t* gB = Bq + (size_t)bn * 256 * K_DIM;

    // staging constants
    const int idx = tid >> 3, p = tid & 7;
    const int rB = (idx & 31) + ((idx >> 5) << 6);
    const int srcX = ((p ^ (idx & 7)) << 4);
    const int dA = tid * 16;
    const int dB = tid * 16 + ((tid >> 8) << 12);

    // fragment-read constants
    const int wr = w >> 2, wc = w & 3;       // 2M x 4N wave grid
    const int lr = l & 15, g = l >> 4;
    const int oLo = (((2 * g) ^ (lr & 7)) << 4);
    const int oHi = (((2 * g + 1) ^ (lr & 7)) << 4);
    const int rowA0 = wr * 128 + lr;
    const int rowB0 = wc * 64 + lr;

    auto stA = [&](int bb, const uint8_t* gsrc, int rbase) {
        const int row = idx + rbase;
        gld16(gsrc + (size_t)row * K_DIM + srcX,
              &lds[bb * 32768 + rbase * 128 + dA]);
    };
    auto stB = [&](int bb, const uint8_t* gsrc, int boff, int r) {
        const int row = rB + boff + (r << 7);
        gld16(gsrc + (size_t)row * K_DIM + srcX,
              &lds[65536 + bb * 32768 + (boff << 7) + (r << 14) + dB]);
    };
    auto ldf = [&](const uint8_t* base, int row) -> i32x8 {
        const uint8_t* q = base + (row << 7);
        i32x4 lo = *(const i32x4*)(q + oLo);
        i32x4 hi = *(const i32x4*)(q + oHi);
        return __builtin_shufflevector(lo, hi, 0, 1, 2, 3, 4, 5, 6, 7);
    };

    f32x4 acc[8][4] = {};
    i32x8 av[4], bv[4];

    // prologue: stage tile 0 -> buf 0 (issue order UA0, UB0, UA1, UB1)
    stA(0, gA, 0);   stA(0, gA, 128);
    stB(0, gB, 0, 0); stB(0, gB, 0, 1);
    stA(0, gA, 64);  stA(0, gA, 192);
    stB(0, gB, 32, 0); stB(0, gB, 32, 1);

    for (int t = 0; t < 31; ++t) {
        const int buf = t & 1, nbuf = buf ^ 1;
        const uint8_t* gAn = gA + (size_t)(t + 1) * 128;
        const uint8_t* gBn = gB + (size_t)(t + 1) * 128;
        const uint8_t* lab = &lds[buf * 32768];
        const uint8_t* lbb = &lds[65536 + buf * 32768];

        // ---- phase 0: UA0(t),UB0(t) ready; stage UA0(t+1)
        asm volatile("s_waitcnt vmcnt(4)" ::: "memory");
        __builtin_amdgcn_s_barrier();
        stA(nbuf, gAn, 0); stA(nbuf, gAn, 128);
        av[0] = ldf(lab, rowA0);      av[1] = ldf(lab, rowA0 + 16);
        av[2] = ldf(lab, rowA0 + 32); av[3] = ldf(lab, rowA0 + 48);
        bv[0] = ldf(lbb, rowB0);      bv[1] = ldf(lbb, rowB0 + 16);
        __builtin_amdgcn_s_setprio(1);
        acc[0][0] = MFMA_MX(av[0], bv[0], acc[0][0]);
        acc[0][1] = MFMA_MX(av[0], bv[1], acc[0][1]);
        acc[1][0] = MFMA_MX(av[1], bv[0], acc[1][0]);
        acc[1][1] = MFMA_MX(av[1], bv[1], acc[1][1]);
        acc[2][0] = MFMA_MX(av[2], bv[0], acc[2][0]);
        acc[2][1] = MFMA_MX(av[2], bv[1], acc[2][1]);
        acc[3][0] = MFMA_MX(av[3], bv[0], acc[3][0]);
        acc[3][1] = MFMA_MX(av[3], bv[1], acc[3][1]);
        __builtin_amdgcn_s_setprio(0);

        // ---- phase 1: UA1(t),UB1(t) ready; stage UB0(t+1)
        asm volatile("s_waitcnt vmcnt(2)" ::: "memory");
        __builtin_amdgcn_s_barrier();
        stB(nbuf, gBn, 0, 0); stB(nbuf, gBn, 0, 1);
        bv[2] = ldf(lbb, rowB0 + 32); bv[3] = ldf(lbb, rowB0 + 48);
        __builtin_amdgcn_s_setprio(1);
        acc[0][2] = MFMA_MX(av[0], bv[2], acc[0][2]);
        acc[0][3] = MFMA_MX(av[0], bv[3], acc[0][3]);
        acc[1][2] = MFMA_MX(av[1], bv[2], acc[1][2]);
        acc[1][3] = MFMA_MX(av[1], bv[3], acc[1][3]);
        acc[2][2] = MFMA_MX(av[2], bv[2], acc[2][2]);
        acc[2][3] = MFMA_MX(av[2], bv[3], acc[2][3]);
        acc[3][2] = MFMA_MX(av[3], bv[2], acc[3][2]);
        acc[3][3] = MFMA_MX(av[3], bv[3], acc[3][3]);
        __builtin_amdgcn_s_setprio(0);

        // ---- phase 2: stage UA1(t+1); read A mb4-7 (completion covered by ph1)
        stA(nbuf, gAn, 64); stA(nbuf, gAn, 192);
        av[0] = ldf(lab, rowA0 + 64); av[1] = ldf(lab, rowA0 + 80);
        av[2] = ldf(lab, rowA0 + 96); av[3] = ldf(lab, rowA0 + 112);
        __builtin_amdgcn_s_setprio(1);
        acc[4][0] = MFMA_MX(av[0], bv[0], acc[4][0]);
        acc[4][1] = MFMA_MX(av[0], bv[1], acc[4][1]);
        acc[5][0] = MFMA_MX(av[1], bv[0], acc[5][0]);
        acc[5][1] = MFMA_MX(av[1], bv[1], acc[5][1]);
        acc[6][0] = MFMA_MX(av[2], bv[0], acc[6][0]);
        acc[6][1] = MFMA_MX(av[2], bv[1], acc[6][1]);
        acc[7][0] = MFMA_MX(av[3], bv[0], acc[7][0]);
        acc[7][1] = MFMA_MX(av[3], bv[1], acc[7][1]);
        __builtin_amdgcn_s_setprio(0);

        // ---- phase 3: stage UB1(t+1)
        stB(nbuf, gBn, 32, 0); stB(nbuf, gBn, 32, 1);
        __builtin_amdgcn_s_setprio(1);
        acc[4][2] = MFMA_MX(av[0], bv[2], acc[4][2]);
        acc[4][3] = MFMA_MX(av[0], bv[3], acc[4][3]);
        acc[5][2] = MFMA_MX(av[1], bv[2], acc[5][2]);
        acc[5][3] = MFMA_MX(av[1], bv[3], acc[5][3]);
        acc[6][2] = MFMA_MX(av[2], bv[2], acc[6][2]);
        acc[6][3] = MFMA_MX(av[2], bv[3], acc[6][3]);
        acc[7][2] = MFMA_MX(av[3], bv[2], acc[7][2]);
        acc[7][3] = MFMA_MX(av[3], bv[3], acc[7][3]);
        __builtin_amdgcn_s_setprio(0);
    }

    // ---- peeled last tile (t=31, buf=1): no stages; drain waits
    {
        const uint8_t* lab = &lds[32768];
        const uint8_t* lbb = &lds[65536 + 32768];

        asm volatile("s_waitcnt vmcnt(4)" ::: "memory");
        __builtin_amdgcn_s_barrier();
        av[0] = ldf(lab, rowA0);      av[1] = ldf(lab, rowA0 + 16);
        av[2] = ldf(lab, rowA0 + 32); av[3] = ldf(lab, rowA0 + 48);
        bv[0] = ldf(lbb, rowB0);      bv[1] = ldf(lbb, rowB0 + 16);
#pragma unroll
        for (int m = 0; m < 4; ++m) {
            acc[m][0] = MFMA_MX(av[m], bv[0], acc[m][0]);
            acc[m][1] = MFMA_MX(av[m], bv[1], acc[m][1]);
        }
        asm volatile("s_waitcnt vmcnt(0)" ::: "memory");
        __builtin_amdgcn_s_barrier();
        bv[2] = ldf(lbb, rowB0 + 32); bv[3] = ldf(lbb, rowB0 + 48);
#pragma unroll
        for (int m = 0; m < 4; ++m) {
            acc[m][2] = MFMA_MX(av[m], bv[2], acc[m][2]);
            acc[m][3] = MFMA_MX(av[m], bv[3], acc[m][3]);
        }
        av[0] = ldf(lab, rowA0 + 64); av[1] = ldf(lab, rowA0 + 80);
        av[2] = ldf(lab, rowA0 + 96); av[3] = ldf(lab, rowA0 + 112);
#pragma unroll
        for (int m = 0; m < 4; ++m) {
            acc[4 + m][0] = MFMA_MX(av[m], bv[0], acc[4 + m][0]);
            acc[4 + m][1] = MFMA_MX(av[m], bv[1], acc[4 + m][1]);
            acc[4 + m][2] = MFMA_MX(av[m], bv[2], acc[4 + m][2]);
            acc[4 + m][3] = MFMA_MX(av[m], bv[3], acc[4 + m][3]);
        }
    }

    // ---- epilogue: scale by (amax_x/448)*(amax_w/448), add bias
    const float ax = fmaxf(__uint_as_float(ws_u[0]), 1e-12f);
    const float aw = fmaxf(__uint_as_float(ws_u[1]), 1e-12f);
    const float inv = (ax * (1.0f / 448.0f)) * (aw * (1.0f / 448.0f));

    const int orow0 = bm * 256 + wr * 128 + g * 4;   // D: row=(lane>>4)*4+reg
    const int ocol0 = bn * 256 + wc * 64 + lr;       // D: col=lane&15
#pragma unroll
    for (int mb = 0; mb < 8; ++mb) {
#pragma unroll
        for (int nb = 0; nb < 4; ++nb) {
            const int col = ocol0 + nb * 16;
            const float bvv = bias[col];
#pragma unroll
            for (int j = 0; j < 4; ++j) {
                const int row = orow0 + mb * 16 + j;
                out[(size_t)row * N_DIM + col] = acc[mb][nb][j] * inv + bvv;
            }
        }
    }
}

// ---------------- launch ----------------
extern "C" void kernel_launch(void* const* d_in, const int* in_sizes, int n_in,
                              void* d_out, int out_size, void* d_ws, size_t ws_size,
                              hipStream_t stream) {
    const float* x    = (const float*)d_in[0];   // [8192, 4096]
    const float* wgt  = (const float*)d_in[1];   // [4096, 4096]
    const float* bias = (const float*)d_in[2];   // [4096]
    float* out = (float*)d_out;                  // [8192, 4096] f32

    unsigned int* ws_u = (unsigned int*)d_ws;
    uint8_t* xq = (uint8_t*)d_ws + 256;
    uint8_t* wq = xq + (size_t)M_DIM * K_DIM;

    hipMemsetAsync(d_ws, 0, 8, stream);          // zero both amax slots

    dim3 ga(1024, 2);
    amax2_kernel<<<ga, 256, 0, stream>>>(x, wgt, ws_u);

    dim3 gq(2048, 2);
    quant2_kernel<<<gq, 256, 0, stream>>>(x, wgt, (unsigned int*)xq,
                                          (unsigned int*)wq, ws_u);

    gemm_fp8_kernel<<<(M_DIM / 256) * (N_DIM / 256), 512, 0, stream>>>(
        xq, wq, bias, ws_u, out);
}

// Round 14
// 211.594 us; speedup vs baseline: 1.0833x; 1.0016x over previous
//
#include <hip/hip_runtime.h>
#include <stdint.h>

#define M_DIM 8192
#define N_DIM 4096
#define K_DIM 4096

typedef float f32x4 __attribute__((ext_vector_type(4)));
typedef int   i32x4 __attribute__((ext_vector_type(4)));
typedef int   i32x8 __attribute__((ext_vector_type(8)));

// ---------------- fused amax (x and w) via uint-bits atomicMax ----------------
__global__ __launch_bounds__(256) void amax2_kernel(const float* __restrict__ x,
                                                    const float* __restrict__ wgt,
                                                    unsigned int* __restrict__ ws_u) {
    const int which = blockIdx.y;
    const float4* p = (const float4*)(which ? wgt : x);
    const int n4 = (which ? N_DIM : M_DIM) * (K_DIM / 4);
    int tid = blockIdx.x * blockDim.x + threadIdx.x;
    int stride = gridDim.x * blockDim.x;
    float m = 0.0f;
    for (int i = tid; i < n4; i += stride) {
        float4 v = p[i];
        m = fmaxf(m, fmaxf(fmaxf(fabsf(v.x), fabsf(v.y)),
                           fmaxf(fabsf(v.z), fabsf(v.w))));
    }
#pragma unroll
    for (int off = 32; off > 0; off >>= 1)
        m = fmaxf(m, __shfl_down(m, off, 64));
    __shared__ float sm[4];
    if ((threadIdx.x & 63) == 0) sm[threadIdx.x >> 6] = m;
    __syncthreads();
    if (threadIdx.x == 0) {
        m = fmaxf(fmaxf(sm[0], sm[1]), fmaxf(sm[2], sm[3]));
        atomicMax(ws_u + which, __float_as_uint(m));  // values >= 0: bit order == float order
    }
}

// ---------------- fused quantize f32 -> fp8 e4m3fn (packed 4/uint) -------------
__global__ __launch_bounds__(256) void quant2_kernel(const float* __restrict__ x,
                                                     const float* __restrict__ wgt,
                                                     unsigned int* __restrict__ xq,
                                                     unsigned int* __restrict__ wq,
                                                     const unsigned int* __restrict__ ws_u) {
    const int which = blockIdx.y;
    const float4* p = (const float4*)(which ? wgt : x);
    unsigned int* outp = which ? wq : xq;
    const int n4 = (which ? N_DIM : M_DIM) * (K_DIM / 4);
    float amax = fmaxf(__uint_as_float(ws_u[which]), 1e-12f);
    float scale = 448.0f / amax;
    int tid = blockIdx.x * blockDim.x + threadIdx.x;
    int stride = gridDim.x * blockDim.x;
    for (int i = tid; i < n4; i += stride) {
        float4 v = p[i];
        float a = fminf(fmaxf(v.x * scale, -448.0f), 448.0f);
        float b = fminf(fmaxf(v.y * scale, -448.0f), 448.0f);
        float c = fminf(fmaxf(v.z * scale, -448.0f), 448.0f);
        float d = fminf(fmaxf(v.w * scale, -448.0f), 448.0f);
        int w = __builtin_amdgcn_cvt_pk_fp8_f32(a, b, 0, false);
        w = __builtin_amdgcn_cvt_pk_fp8_f32(c, d, w, true);
        outp[i] = (unsigned int)w;
    }
}

// ---------------- MX-fp8 GEMM, 256x256 tile, 4-phase pipelined ----------------
// R4/R13's measured-best schedule, with fragment reads converted to
// base-pointer + compile-time-immediate ds_read offsets (swizzle key row&7 ==
// lr&7 is thread-constant because all fragment rows differ by multiples of
// 16, so per-tile only 4 base pointers are computed; all 48 ds_read_b128 use
// literal offsets that fold into the 16-bit ds offset field -> ~100 fewer
// VALU insts/tile).
__device__ __forceinline__ void gld16(const void* g, void* l) {
    __builtin_amdgcn_global_load_lds(
        (const __attribute__((address_space(1))) void*)g,
        (__attribute__((address_space(3))) void*)l, 16, 0, 0);
}

__device__ __forceinline__ i32x8 ld2(const uint8_t* bl, const uint8_t* bh, int off) {
    i32x4 lo = *(const i32x4*)(bl + off);   // off is a call-site literal ->
    i32x4 hi = *(const i32x4*)(bh + off);   // folds into ds_read immediate
    return __builtin_shufflevector(lo, hi, 0, 1, 2, 3, 4, 5, 6, 7);
}

#define MFMA_MX(a, b, c) __builtin_amdgcn_mfma_scale_f32_16x16x128_f8f6f4( \
    (a), (b), (c), 0, 0, 0, 0x7F7F7F7F, 0, 0x7F7F7F7F)

// LDS: A bufs at [0,32K),[32K,64K); B bufs at [64K,96K),[96K,128K).
// Per-tensor tile [256 rows][128 B], 16B-chunk XOR swizzle (chunk ^= row&7),
// staged linearly (pre-swizzled global source), read with XOR on address.
// Pipeline: tile t read from buf t&1; tile t+1's 4 units staged one-per-phase
// into buf^1. Counted vmcnt only: ledger (2 loads/unit, issue order
// UA0,UB0,UA1,UB1 per tile) => phase0 needs UA0,UB0 -> vmcnt(4);
// phase1 needs UA1,UB1 -> vmcnt(2). Never 0 in the main loop.
__global__ __launch_bounds__(512, 2) void gemm_fp8_kernel(
    const uint8_t* __restrict__ Aq,   // [M][K] fp8
    const uint8_t* __restrict__ Bq,   // [N][K] fp8
    const float* __restrict__ bias,   // [N]
    const unsigned int* __restrict__ ws_u,
    float* __restrict__ out)          // [M][N] f32
{
    __shared__ uint8_t lds[131072];

    const int tid = threadIdx.x;
    const int w = tid >> 6, l = tid & 63;

    // XCD swizzle (512 blocks, %8==0): 32 M-tiles x 16 N-tiles
    const int cpx = (int)gridDim.x >> 3;
    const int bid = (int)blockIdx.x;
    const int swz = (bid & 7) * cpx + (bid >> 3);
    const int bm = swz >> 4, bn = swz & 15;

    const uint8_t* gA = Aq + (size_t)bm * 256 * K_DIM;
    const uint8_t* gB = Bq + (size_t)bn * 256 * K_DIM;

    // staging constants
    const int idx = tid >> 3, p = tid & 7;
    const int rB = (idx & 31) + ((idx >> 5) << 6);
    const int srcX = ((p ^ (idx & 7)) << 4);
    const int dA = tid * 16;
    const int dB = tid * 16 + ((tid >> 8) << 12);

    // fragment-read constants
    const int wr = w >> 2, wc = w & 3;       // 2M x 4N wave grid
    const int lr = l & 15, g = l >> 4;
    const int oLo = (((2 * g) ^ (lr & 7)) << 4);
    const int oHi = (((2 * g + 1) ^ (lr & 7)) << 4);
    const int rowA0 = wr * 128 + lr;
    const int rowB0 = wc * 64 + lr;

    // per-thread fragment base offsets (row&7 is constant across all
    // fragment rows -> swizzle folds into these 4 offsets)
    const int aOffL = (rowA0 << 7) + oLo, aOffH = (rowA0 << 7) + oHi;
    const int bOffL = (rowB0 << 7) + oLo, bOffH = (rowB0 << 7) + oHi;

    auto stA = [&](int bb, const uint8_t* gsrc, int rbase) {
        const int row = idx + rbase;
        gld16(gsrc + (size_t)row * K_DIM + srcX,
              &lds[bb * 32768 + rbase * 128 + dA]);
    };
    auto stB = [&](int bb, const uint8_t* gsrc, int boff, int r) {
        const int row = rB + boff + (r << 7);
        gld16(gsrc + (size_t)row * K_DIM + srcX,
              &lds[65536 + bb * 32768 + (boff << 7) + (r << 14) + dB]);
    };

    f32x4 acc[8][4] = {};
    i32x8 av[4], bv[4];

    // prologue: stage tile 0 -> buf 0 (issue order UA0, UB0, UA1, UB1)
    stA(0, gA, 0);   stA(0, gA, 128);
    stB(0, gB, 0, 0); stB(0, gB, 0, 1);
    stA(0, gA, 64);  stA(0, gA, 192);
    stB(0, gB, 32, 0); stB(0, gB, 32, 1);

    for (int t = 0; t < 31; ++t) {
        const int buf = t & 1, nbuf = buf ^ 1;
        const uint8_t* gAn = gA + (size_t)(t + 1) * 128;
        const uint8_t* gBn = gB + (size_t)(t + 1) * 128;
        // fragment base pointers for this tile's buffer (immediate-offset reads)
        const uint8_t* qaL = &lds[buf * 32768] + aOffL;
        const uint8_t* qaH = &lds[buf * 32768] + aOffH;
        const uint8_t* qbL = &lds[65536 + buf * 32768] + bOffL;
        const uint8_t* qbH = &lds[65536 + buf * 32768] + bOffH;

        // ---- phase 0: UA0(t),UB0(t) ready; stage UA0(t+1)
        asm volatile("s_waitcnt vmcnt(4)" ::: "memory");
        __builtin_amdgcn_s_barrier();
        stA(nbuf, gAn, 0); stA(nbuf, gAn, 128);
        av[0] = ld2(qaL, qaH, 0);     av[1] = ld2(qaL, qaH, 2048);
        av[2] = ld2(qaL, qaH, 4096);  av[3] = ld2(qaL, qaH, 6144);
        bv[0] = ld2(qbL, qbH, 0);     bv[1] = ld2(qbL, qbH, 2048);
        __builtin_amdgcn_s_setprio(1);
        acc[0][0] = MFMA_MX(av[0], bv[0], acc[0][0]);
        acc[0][1] = MFMA_MX(av[0], bv[1], acc[0][1]);
        acc[1][0] = MFMA_MX(av[1], bv[0], acc[1][0]);
        acc[1][1] = MFMA_MX(av[1], bv[1], acc[1][1]);
        acc[2][0] = MFMA_MX(av[2], bv[0], acc[2][0]);
        acc[2][1] = MFMA_MX(av[2], bv[1], acc[2][1]);
        acc[3][0] = MFMA_MX(av[3], bv[0], acc[3][0]);
        acc[3][1] = MFMA_MX(av[3], bv[1], acc[3][1]);
        __builtin_amdgcn_s_setprio(0);

        // ---- phase 1: UA1(t),UB1(t) ready; stage UB0(t+1)
        asm volatile("s_waitcnt vmcnt(2)" ::: "memory");
        __builtin_amdgcn_s_barrier();
        stB(nbuf, gBn, 0, 0); stB(nbuf, gBn, 0, 1);
        bv[2] = ld2(qbL, qbH, 4096);  bv[3] = ld2(qbL, qbH, 6144);
        __builtin_amdgcn_s_setprio(1);
        acc[0][2] = MFMA_MX(av[0], bv[2], acc[0][2]);
        acc[0][3] = MFMA_MX(av[0], bv[3], acc[0][3]);
        acc[1][2] = MFMA_MX(av[1], bv[2], acc[1][2]);
        acc[1][3] = MFMA_MX(av[1], bv[3], acc[1][3]);
        acc[2][2] = MFMA_MX(av[2], bv[2], acc[2][2]);
        acc[2][3] = MFMA_MX(av[2], bv[3], acc[2][3]);
        acc[3][2] = MFMA_MX(av[3], bv[2], acc[3][2]);
        acc[3][3] = MFMA_MX(av[3], bv[3], acc[3][3]);
        __builtin_amdgcn_s_setprio(0);

        // ---- phase 2: stage UA1(t+1); read A mb4-7 (completion covered by ph1)
        stA(nbuf, gAn, 64); stA(nbuf, gAn, 192);
        av[0] = ld2(qaL, qaH, 8192);  av[1] = ld2(qaL, qaH, 10240);
        av[2] = ld2(qaL, qaH, 12288); av[3] = ld2(qaL, qaH, 14336);
        __builtin_amdgcn_s_setprio(1);
        acc[4][0] = MFMA_MX(av[0], bv[0], acc[4][0]);
        acc[4][1] = MFMA_MX(av[0], bv[1], acc[4][1]);
        acc[5][0] = MFMA_MX(av[1], bv[0], acc[5][0]);
        acc[5][1] = MFMA_MX(av[1], bv[1], acc[5][1]);
        acc[6][0] = MFMA_MX(av[2], bv[0], acc[6][0]);
        acc[6][1] = MFMA_MX(av[2], bv[1], acc[6][1]);
        acc[7][0] = MFMA_MX(av[3], bv[0], acc[7][0]);
        acc[7][1] = MFMA_MX(av[3], bv[1], acc[7][1]);
        __builtin_amdgcn_s_setprio(0);

        // ---- phase 3: stage UB1(t+1)
        stB(nbuf, gBn, 32, 0); stB(nbuf, gBn, 32, 1);
        __builtin_amdgcn_s_setprio(1);
        acc[4][2] = MFMA_MX(av[0], bv[2], acc[4][2]);
        acc[4][3] = MFMA_MX(av[0], bv[3], acc[4][3]);
        acc[5][2] = MFMA_MX(av[1], bv[2], acc[5][2]);
        acc[5][3] = MFMA_MX(av[1], bv[3], acc[5][3]);
        acc[6][2] = MFMA_MX(av[2], bv[2], acc[6][2]);
        acc[6][3] = MFMA_MX(av[2], bv[3], acc[6][3]);
        acc[7][2] = MFMA_MX(av[3], bv[2], acc[7][2]);
        acc[7][3] = MFMA_MX(av[3], bv[3], acc[7][3]);
        __builtin_amdgcn_s_setprio(0);
    }

    // ---- peeled last tile (t=31, buf=1): no stages; drain waits
    {
        const uint8_t* qaL = &lds[32768] + aOffL;
        const uint8_t* qaH = &lds[32768] + aOffH;
        const uint8_t* qbL = &lds[65536 + 32768] + bOffL;
        const uint8_t* qbH = &lds[65536 + 32768] + bOffH;

        asm volatile("s_waitcnt vmcnt(4)" ::: "memory");
        __builtin_amdgcn_s_barrier();
        av[0] = ld2(qaL, qaH, 0);     av[1] = ld2(qaL, qaH, 2048);
        av[2] = ld2(qaL, qaH, 4096);  av[3] = ld2(qaL, qaH, 6144);
        bv[0] = ld2(qbL, qbH, 0);     bv[1] = ld2(qbL, qbH, 2048);
#pragma unroll
        for (int m = 0; m < 4; ++m) {
            acc[m][0] = MFMA_MX(av[m], bv[0], acc[m][0]);
            acc[m][1] = MFMA_MX(av[m], bv[1], acc[m][1]);
        }
        asm volatile("s_waitcnt vmcnt(0)" ::: "memory");
        __builtin_amdgcn_s_barrier();
        bv[2] = ld2(qbL, qbH, 4096);  bv[3] = ld2(qbL, qbH, 6144);
#pragma unroll
        for (int m = 0; m < 4; ++m) {
            acc[m][2] = MFMA_MX(av[m], bv[2], acc[m][2]);
            acc[m][3] = MFMA_MX(av[m], bv[3], acc[m][3]);
        }
        av[0] = ld2(qaL, qaH, 8192);  av[1] = ld2(qaL, qaH, 10240);
        av[2] = ld2(qaL, qaH, 12288); av[3] = ld2(qaL, qaH, 14336);
#pragma unroll
        for (int m = 0; m < 4; ++m) {
            acc[4 + m][0] = MFMA_MX(av[m], bv[0], acc[4 + m][0]);
            acc[4 + m][1] = MFMA_MX(av[m], bv[1], acc[4 + m][1]);
            acc[4 + m][2] = MFMA_MX(av[m], bv[2], acc[4 + m][2]);
            acc[4 + m][3] = MFMA_MX(av[m], bv[3], acc[4 + m][3]);
        }
    }

    // ---- epilogue: scale by (amax_x/448)*(amax_w/448), add bias
    const float ax = fmaxf(__uint_as_float(ws_u[0]), 1e-12f);
    const float aw = fmaxf(__uint_as_float(ws_u[1]), 1e-12f);
    const float inv = (ax * (1.0f / 448.0f)) * (aw * (1.0f / 448.0f));

    const int orow0 = bm * 256 + wr * 128 + g * 4;   // D: row=(lane>>4)*4+reg
    const int ocol0 = bn * 256 + wc * 64 + lr;       // D: col=lane&15
#pragma unroll
    for (int mb = 0; mb < 8; ++mb) {
#pragma unroll
        for (int nb = 0; nb < 4; ++nb) {
            const int col = ocol0 + nb * 16;
            const float bvv = bias[col];
#pragma unroll
            for (int j = 0; j < 4; ++j) {
                const int row = orow0 + mb * 16 + j;
                out[(size_t)row * N_DIM + col] = acc[mb][nb][j] * inv + bvv;
            }
        }
    }
}

// ---------------- launch ----------------
extern "C" void kernel_launch(void* const* d_in, const int* in_sizes, int n_in,
                              void* d_out, int out_size, void* d_ws, size_t ws_size,
                              hipStream_t stream) {
    const float* x    = (const float*)d_in[0];   // [8192, 4096]
    const float* wgt  = (const float*)d_in[1];   // [4096, 4096]
    const float* bias = (const float*)d_in[2];   // [4096]
    float* out = (float*)d_out;                  // [8192, 4096] f32

    unsigned int* ws_u = (unsigned int*)d_ws;
    uint8_t* xq = (uint8_t*)d_ws + 256;
    uint8_t* wq = xq + (size_t)M_DIM * K_DIM;

    hipMemsetAsync(d_ws, 0, 8, stream);          // zero both amax slots

    dim3 ga(1024, 2);
    amax2_kernel<<<ga, 256, 0, stream>>>(x, wgt, ws_u);

    dim3 gq(2048, 2);
    quant2_kernel<<<gq, 256, 0, stream>>>(x, wgt, (unsigned int*)xq,
                                          (unsigned int*)wq, ws_u);

    gemm_fp8_kernel<<<(M_DIM / 256) * (N_DIM / 256), 512, 0, stream>>>(
        xq, wq, bias, ws_u, out);
}